// Round 1
// baseline (84.922 us; speedup 1.0000x reference)
//
#include <hip/hip_runtime.h>

#define DIM    64      // CELL_DIM
#define NCELLS 512
#define CHUNK  256     // cells staged per LDS chunk
#define ROWS_PER_BLOCK 16
#define NROWS  8192

// Block: 256 threads = 4 waves. Wave w owns rows rowBase..rowBase+3.
// Lane l owns cells {ch*256 + 4l .. 4l+3} per chunk ch.
// Accumulators are named float4s (NOT arrays) — local arrays with loop-variable
// indices land in scratch.
// R2 change: x is cached in 4 VGPRs/lane (lane l holds x[row][l]) and broadcast
// with v_readlane — the inner K loop has ZERO global loads (previously 128
// global float4 loads/thread caused vmcnt stalls at 2 waves/SIMD occupancy).
__global__ __launch_bounds__(256, 2)
void placecells_kernel(const float* __restrict__ x,
                       const float* __restrict__ pc,
                       float* __restrict__ out)
{
    __shared__ float pcT[DIM * CHUNK];   // 64 KB, [k][cell] XOR-swizzled

    const int tid = (int)threadIdx.x;
    const int l   = tid & 63;
    const int w   = __builtin_amdgcn_readfirstlane(tid >> 6);
    const int rowBase = (int)blockIdx.x * ROWS_PER_BLOCK + w * 4;

    // Per-lane x cache: lane l holds x[rowBase+r][l] for r=0..3 (4 VGPRs).
    // Coalesced: 64 lanes * 4 B = one 256 B line per row.
    const float xr0 = x[(rowBase + 0) * DIM + l];
    const float xr1 = x[(rowBase + 1) * DIM + l];
    const float xr2 = x[(rowBase + 2) * DIM + l];
    const float xr3 = x[(rowBase + 3) * DIM + l];

    // d{row}{chunk}: 4 cells each -> 32 accumulator VGPRs, promotion-safe
    float4 d00{0,0,0,0}, d10{0,0,0,0}, d20{0,0,0,0}, d30{0,0,0,0};
    float4 d01{0,0,0,0}, d11{0,0,0,0}, d21{0,0,0,0}, d31{0,0,0,0};

    auto do_chunk = [&](int ch, float4& a0, float4& a1, float4& a2, float4& a3) {
        // ---- stage chunk: global [cell][k] -> LDS pcT[k][cell], swizzled ----
        #pragma unroll 4
        for (int i = 0; i < 16; ++i) {
            int idx = i * 256 + tid;
            int cl  = idx >> 4;           // cell within chunk, 0..255
            int k4  = idx & 15;           // k-quad (coalesced 1KB/wave)
            float4 v = *(const float4*)(pc + (ch * CHUNK + cl) * DIM + k4 * 4);
            int pq = (cl >> 2) ^ k4;      // bank swizzle
            float* p = &pcT[(k4 * 4) * CHUNK + pq * 4 + (cl & 3)];
            p[0 * CHUNK] = v.x;
            p[1 * CHUNK] = v.y;
            p[2 * CHUNK] = v.z;
            p[3 * CHUNK] = v.w;
        }
        __syncthreads();

        // ---- K loop: 4 rows x 4 cells per k, x broadcast via readlane ----
        #pragma unroll 4
        for (int k4 = 0; k4 < 16; ++k4) {
            const int pq4 = (l ^ k4) * 4; // undo swizzle: logical quad = l
            #pragma unroll
            for (int j = 0; j < 4; ++j) {
                const int k = k4 * 4 + j;
                float4 pv = *(const float4*)(&pcT[k * CHUNK + pq4]);
                float x0 = __int_as_float(__builtin_amdgcn_readlane(__float_as_int(xr0), k));
                float x1 = __int_as_float(__builtin_amdgcn_readlane(__float_as_int(xr1), k));
                float x2 = __int_as_float(__builtin_amdgcn_readlane(__float_as_int(xr2), k));
                float x3 = __int_as_float(__builtin_amdgcn_readlane(__float_as_int(xr3), k));
                a0.x += fabsf(x0 - pv.x); a0.y += fabsf(x0 - pv.y);
                a0.z += fabsf(x0 - pv.z); a0.w += fabsf(x0 - pv.w);
                a1.x += fabsf(x1 - pv.x); a1.y += fabsf(x1 - pv.y);
                a1.z += fabsf(x1 - pv.z); a1.w += fabsf(x1 - pv.w);
                a2.x += fabsf(x2 - pv.x); a2.y += fabsf(x2 - pv.y);
                a2.z += fabsf(x2 - pv.z); a2.w += fabsf(x2 - pv.w);
                a3.x += fabsf(x3 - pv.x); a3.y += fabsf(x3 - pv.y);
                a3.z += fabsf(x3 - pv.z); a3.w += fabsf(x3 - pv.w);
            }
        }
    };

    do_chunk(0, d00, d10, d20, d30);
    __syncthreads();
    do_chunk(1, d01, d11, d21, d31);

    // ---- softmax per row over 512 cells (one wave holds a whole row) ----
    auto finish_row = [&](float4 a, float4 b, int r) {
        // min L1 == min d^2 (d >= 0) -> exact max-subtraction
        float mn = fminf(fminf(fminf(a.x, a.y), fminf(a.z, a.w)),
                         fminf(fminf(b.x, b.y), fminf(b.z, b.w)));
        #pragma unroll
        for (int off = 32; off > 0; off >>= 1)
            mn = fminf(mn, __shfl_xor(mn, off, 64));
        float m2 = mn * mn;

        float e0 = __expf(0.5f * (m2 - a.x * a.x));
        float e1 = __expf(0.5f * (m2 - a.y * a.y));
        float e2 = __expf(0.5f * (m2 - a.z * a.z));
        float e3 = __expf(0.5f * (m2 - a.w * a.w));
        float e4 = __expf(0.5f * (m2 - b.x * b.x));
        float e5 = __expf(0.5f * (m2 - b.y * b.y));
        float e6 = __expf(0.5f * (m2 - b.z * b.z));
        float e7 = __expf(0.5f * (m2 - b.w * b.w));
        float s = ((e0 + e1) + (e2 + e3)) + ((e4 + e5) + (e6 + e7));
        #pragma unroll
        for (int off = 32; off > 0; off >>= 1)
            s += __shfl_xor(s, off, 64);
        float inv = 1.0f / s;

        float* orow = out + (size_t)(rowBase + r) * NCELLS;
        *(float4*)(orow + 4 * l)         = make_float4(e0 * inv, e1 * inv, e2 * inv, e3 * inv);
        *(float4*)(orow + CHUNK + 4 * l) = make_float4(e4 * inv, e5 * inv, e6 * inv, e7 * inv);
    };
    finish_row(d00, d01, 0);
    finish_row(d10, d11, 1);
    finish_row(d20, d21, 2);
    finish_row(d30, d31, 3);
}

extern "C" void kernel_launch(void* const* d_in, const int* in_sizes, int n_in,
                              void* d_out, int out_size, void* d_ws, size_t ws_size,
                              hipStream_t stream)
{
    const float* x  = (const float*)d_in[0];   // (8192, 64) fp32
    const float* pc = (const float*)d_in[1];   // (512, 64) fp32
    float* out = (float*)d_out;                // (8192, 512) fp32
    placecells_kernel<<<dim3(NROWS / ROWS_PER_BLOCK), dim3(256), 0, stream>>>(x, pc, out);
}